// Round 10
// baseline (897.937 us; speedup 1.0000x reference)
//
#include <hip/hip_runtime.h>
#include <hip/hip_bf16.h>
#include <cstdint>
#include <cstddef>

// ---------------- problem constants ----------------
#define M_TOK 4096          // B*S = 4*1024 tokens
#define HID   1024
#define NHEAD 16002
#define NHEAD_PAD 16128     // 126*128
#define P0    256
#define N0    12000
#define N0_PAD 12032        // 94*128
#define P1    64
#define N1    8000
#define N1_PAD 8192         // 64*128
#define PFUSE 384           // fused proj width: 256 + 128(pad of 64)
#define PREAL 320           // real cols in fused proj: 256 + 64

typedef unsigned char u8;
typedef float f32x4 __attribute__((ext_vector_type(4)));
typedef int   i32x4 __attribute__((ext_vector_type(4)));
typedef int   i32x8 __attribute__((ext_vector_type(8)));

// async global->LDS, 16B per lane; lds ptr = wave-uniform base, HW scatters lane*16.
__device__ __forceinline__ void load16(const void* g, void* l) {
    __builtin_amdgcn_global_load_lds(
        (__attribute__((address_space(1))) void*)g,
        (__attribute__((address_space(3))) void*)l,
        16, 0, 0);
}

// HW fp8 conversion (gfx950 OCP e4m3, RNE+sat) — guarantees v_cvt_pk_fp8_f32,
// never the ~30-op software fallback of the __hip_fp8_e4m3 constructor.
__device__ __forceinline__ u8 to_e4m3(float f) {
    return (u8)(__builtin_amdgcn_cvt_pk_fp8_f32(f, f, 0, false) & 0xff);
}
__device__ __forceinline__ unsigned cvt4(float x, float y, float z, float w) {
    int r = __builtin_amdgcn_cvt_pk_fp8_f32(x, y, 0, false);
    r = __builtin_amdgcn_cvt_pk_fp8_f32(z, w, r, true);
    return (unsigned)r;
}

__device__ __forceinline__ float aload(const float* p) {
    return __hip_atomic_load(p, __ATOMIC_RELAXED, __HIP_MEMORY_SCOPE_AGENT);
}

union Frag { struct { i32x4 lo, hi; } half; i32x8 v; };

// =====================================================================
// Round-10 lse3: GEMM core verbatim round-9 (BM=256 x BN=128, BK=128,
// 8 waves of the proven 64x64 wave tile, single-buffered 48 KB LDS,
// 2-barrier loop, 2 blocks/CU). NEW: finalize fused in via
// threadfence -> device atomic counter -> last-block pattern (saves a
// dispatch + its launch gap). Last block reads the accumulators with
// agent-scope acquire loads (cross-XCD visibility of other blocks'
// device-scope atomicAdds).
// =====================================================================
struct Seg {
    const u8* A; int lda;
    const u8* BT; int ldb;
    const float* bias; int K; int realN;
    const int* tgt; float* sumexp; float* lab;
    int nblk;   // 16 m-tiles x NT n-tiles(128), NT even; nblk % 32 == 0
};

__launch_bounds__(512, 4)
__global__ void gemm_lse3(Seg s0, Seg s1, Seg s2,
                          const int* __restrict__ labels, float* __restrict__ acc6,
                          int* __restrict__ cnt, float* __restrict__ out, int nblkTotal) {
    __shared__ __align__(16) u8 As[32768];   // 256 x 128
    __shared__ __align__(16) u8 Bs[16384];   // 128 x 128

    int b = blockIdx.x;
    Seg sg; int rel;
    if (b < s0.nblk)                { sg = s0; rel = b; }
    else if (b < s0.nblk + s1.nblk) { sg = s1; rel = b - s0.nblk; }
    else                            { sg = s2; rel = b - s0.nblk - s1.nblk; }
    // L2-locality swizzle: 32-block groups = 16 m-tiles x 2 n-tiles.
    int pair = rel >> 5, inner = rel & 31;
    int m0 = (inner >> 1) * 256;
    int n0 = (pair * 2 + (inner & 1)) * 128;

    const int lda = sg.lda, ldb = sg.ldb;
    const int tid  = threadIdx.x;
    const int lane = tid & 63;
    const int wave = tid >> 6;          // 0..7
    const int wm = wave >> 1, wn = wave & 1;
    const int q = lane >> 4, lrow = lane & 15;
    const int sw = lrow & 7;

    // A staging: 2048 granules (256 rows x 8), 4 loads/thread.
    // B staging: 1024 granules (128 rows x 8), 2 loads/thread.
    int aofs[4], abase[4], bofs[2], bbase[2];
    #pragma unroll
    for (int p = 0; p < 4; p++) {
        int pg = wave * 256 + p * 64 + lane;          // 0..2047
        int row = pg >> 3, gcol = (pg & 7) ^ (row & 7);
        aofs[p]  = row * lda + gcol * 16;
        abase[p] = (wave * 256 + p * 64) * 16;
    }
    #pragma unroll
    for (int p = 0; p < 2; p++) {
        int pg = wave * 128 + p * 64 + lane;          // 0..1023
        int row = pg >> 3, gcol = (pg & 7) ^ (row & 7);
        bofs[p]  = row * ldb + gcol * 16;
        bbase[p] = (wave * 128 + p * 64) * 16;
    }

    f32x4 acc[4][4];
    #pragma unroll
    for (int mt = 0; mt < 4; mt++)
        #pragma unroll
        for (int nt = 0; nt < 4; nt++)
            acc[mt][nt] = (f32x4)(0.0f);

    const u8* Ab = sg.A  + (size_t)m0 * lda;
    const u8* Bb = sg.BT + (size_t)n0 * ldb;

    // fragment LDS byte offsets; +t*2048 per 16-row subtile.
    const int aLo = ((wm * 64 + lrow) * 8 + ((2 * q)     ^ sw)) * 16;
    const int aHi = ((wm * 64 + lrow) * 8 + ((2 * q + 1) ^ sw)) * 16;
    const int bLo = ((wn * 64 + lrow) * 8 + ((2 * q)     ^ sw)) * 16;
    const int bHi = ((wn * 64 + lrow) * 8 + ((2 * q + 1) ^ sw)) * 16;

    for (int k0 = 0; k0 < sg.K; k0 += 128) {
        #pragma unroll
        for (int p = 0; p < 4; p++)
            load16(Ab + k0 + aofs[p], As + abase[p]);
        #pragma unroll
        for (int p = 0; p < 2; p++)
            load16(Bb + k0 + bofs[p], Bs + bbase[p]);
        __syncthreads();   // includes vmcnt(0) drain; 2nd block/CU covers it

        Frag fb[4];
        #pragma unroll
        for (int t = 0; t < 4; t++) {
            fb[t].half.lo = *reinterpret_cast<const i32x4*>(Bs + bLo + t * 2048);
            fb[t].half.hi = *reinterpret_cast<const i32x4*>(Bs + bHi + t * 2048);
        }
        Frag fa[2];
        fa[0].half.lo = *reinterpret_cast<const i32x4*>(As + aLo);
        fa[0].half.hi = *reinterpret_cast<const i32x4*>(As + aHi);
        #pragma unroll
        for (int mt = 0; mt < 4; mt++) {
            if (mt < 3) {
                fa[(mt + 1) & 1].half.lo = *reinterpret_cast<const i32x4*>(As + aLo + (mt + 1) * 2048);
                fa[(mt + 1) & 1].half.hi = *reinterpret_cast<const i32x4*>(As + aHi + (mt + 1) * 2048);
            }
            #pragma unroll
            for (int nt = 0; nt < 4; nt++)
                acc[mt][nt] = __builtin_amdgcn_mfma_scale_f32_16x16x128_f8f6f4(
                    fa[mt & 1].v, fb[nt].v, acc[mt][nt],
                    0, 0,                      // cbsz/blgp = fp8 e4m3
                    0, 0x7F7F7F7F,             // A scale: 2^0
                    0, 0x7A7A7A7A);            // B scale: 2^-5
        }
        __syncthreads();   // reads retired before next overwrite
    }

    // ---- epilogue: C/D (16x16): col = lane&15, row = (lane>>4)*4 + reg
    int colg[4]; float bias_v[4];
    #pragma unroll
    for (int nt = 0; nt < 4; nt++) {
        colg[nt] = n0 + wn * 64 + nt * 16 + lrow;
        bias_v[nt] = (colg[nt] < sg.realN) ? sg.bias[colg[nt]] : 0.0f;
    }

    float* sred = reinterpret_cast<float*>(As);   // [2][256], reuse A LDS

    #pragma unroll
    for (int mt = 0; mt < 4; mt++) {
        int rloc = wm * 64 + mt * 16 + q * 4;     // token row within tile (0..255)
        #pragma unroll
        for (int r = 0; r < 4; r++) {
            int tok = m0 + rloc + r;
            int tg = sg.tgt[tok];
            float ps = 0.0f;
            #pragma unroll
            for (int nt = 0; nt < 4; nt++) {
                if (colg[nt] < sg.realN) {
                    float logit = acc[mt][nt][r] + bias_v[nt];
                    ps += __expf(logit);
                    if (colg[nt] == tg) atomicAdd(&sg.lab[tok], logit);
                }
            }
            ps += __shfl_xor(ps, 1);
            ps += __shfl_xor(ps, 2);
            ps += __shfl_xor(ps, 4);
            ps += __shfl_xor(ps, 8);
            // slice write: (wn, row) written by exactly one lane
            if (lrow == 0) sred[wn * 256 + rloc + r] = ps;
        }
    }
    __syncthreads();
    if (tid < 256) {
        float v = sred[tid] + sred[256 + tid];
        atomicAdd(&sg.sumexp[m0 + tid], v);
    }

    // ---- fused finalize: last block computes the mean loss ----
    __threadfence();                              // release my global writes
    __shared__ int lastBlk;
    __syncthreads();                              // all threads' adds issued+fenced
    if (tid == 0) {
        int old = __hip_atomic_fetch_add(cnt, 1, __ATOMIC_ACQ_REL, __HIP_MEMORY_SCOPE_AGENT);
        lastBlk = (old == nblkTotal - 1) ? 1 : 0;
    }
    __syncthreads();
    if (lastBlk) {
        float part = 0.0f;
        for (int t = tid; t < M_TOK; t += 512) {
            int lbl = labels[t];
            if (lbl != 0) {
                float l = logf(aload(&acc6[t])) - aload(&acc6[M_TOK + t]);
                if (lbl >= 16000 && lbl < 28000)
                    l += logf(aload(&acc6[2 * M_TOK + t])) - aload(&acc6[3 * M_TOK + t]);
                else if (lbl >= 28000)
                    l += logf(aload(&acc6[4 * M_TOK + t])) - aload(&acc6[5 * M_TOK + t]);
                part += l;
            }
        }
        #pragma unroll
        for (int o = 1; o < 64; o <<= 1) part += __shfl_xor(part, o);
        float* red = reinterpret_cast<float*>(Bs);
        if ((tid & 63) == 0) red[tid >> 6] = part;
        __syncthreads();
        if (tid == 0) {
            float s = 0.0f;
            #pragma unroll
            for (int i = 0; i < 8; i++) s += red[i];
            out[0] = s * (1.0f / (float)M_TOK);
        }
    }
}

// =====================================================================
// proj GEMM body (proven 128x128, 8 waves of 64x32), runs as blocks of
// the fused prep2 dispatch.
// =====================================================================
__device__ __forceinline__ void proj_body(const u8* __restrict__ A, const u8* __restrict__ BT,
                                          const float* __restrict__ bias, u8* __restrict__ out,
                                          int m0, int n0, u8* As, u8* Bs) {
    const int lda = HID, ldb = HID, ldo = PFUSE;
    const int tid  = threadIdx.x;
    const int lane = tid & 63;
    const int wave = tid >> 6;          // 0..7
    const int wm = wave >> 2, wn = wave & 3;
    const int q = lane >> 4, lrow = lane & 15;
    const int sw = lrow & 7;

    int aofs[2], bofs[2], lbase[2];
    #pragma unroll
    for (int p = 0; p < 2; p++) {
        int pg = wave * 128 + p * 64 + lane;
        int row = pg >> 3, gcol = (pg & 7) ^ (row & 7);
        aofs[p]  = row * lda + gcol * 16;
        bofs[p]  = row * ldb + gcol * 16;
        lbase[p] = (wave * 128 + p * 64) * 16;
    }

    f32x4 acc[4][2];
    #pragma unroll
    for (int mt = 0; mt < 4; mt++)
        #pragma unroll
        for (int nt = 0; nt < 2; nt++)
            acc[mt][nt] = (f32x4)(0.0f);

    const u8* Ab = A  + (size_t)m0 * lda;
    const u8* Bb = BT + (size_t)n0 * ldb;

    const int aLo = ((wm * 64 + lrow) * 8 + ((2 * q)     ^ sw)) * 16;
    const int aHi = ((wm * 64 + lrow) * 8 + ((2 * q + 1) ^ sw)) * 16;
    const int bLo = ((wn * 32 + lrow) * 8 + ((2 * q)     ^ sw)) * 16;
    const int bHi = ((wn * 32 + lrow) * 8 + ((2 * q + 1) ^ sw)) * 16;

    for (int k0 = 0; k0 < HID; k0 += 128) {
        #pragma unroll
        for (int p = 0; p < 2; p++) {
            load16(Ab + k0 + aofs[p], As + lbase[p]);
            load16(Bb + k0 + bofs[p], Bs + lbase[p]);
        }
        __syncthreads();
        Frag fb[2];
        #pragma unroll
        for (int t = 0; t < 2; t++) {
            fb[t].half.lo = *reinterpret_cast<const i32x4*>(Bs + bLo + t * 2048);
            fb[t].half.hi = *reinterpret_cast<const i32x4*>(Bs + bHi + t * 2048);
        }
        #pragma unroll
        for (int mt = 0; mt < 4; mt++) {
            Frag fa;
            fa.half.lo = *reinterpret_cast<const i32x4*>(As + aLo + mt * 2048);
            fa.half.hi = *reinterpret_cast<const i32x4*>(As + aHi + mt * 2048);
            #pragma unroll
            for (int nt = 0; nt < 2; nt++)
                acc[mt][nt] = __builtin_amdgcn_mfma_scale_f32_16x16x128_f8f6f4(
                    fa.v, fb[nt].v, acc[mt][nt],
                    0, 0, 0, 0x7F7F7F7F, 0, 0x7A7A7A7A);
        }
        __syncthreads();
    }

    int colg[2]; float bias_v[2];
    #pragma unroll
    for (int nt = 0; nt < 2; nt++) {
        colg[nt] = n0 + wn * 32 + nt * 16 + lrow;
        bias_v[nt] = (colg[nt] < PREAL) ? bias[colg[nt]] : 0.0f;
    }
    #pragma unroll
    for (int mt = 0; mt < 4; mt++) {
        int rowb = m0 + wm * 64 + mt * 16 + q * 4;
        #pragma unroll
        for (int r = 0; r < 4; r++) {
            int tok = rowb + r;
            #pragma unroll
            for (int nt = 0; nt < 2; nt++)
                out[(size_t)tok * ldo + colg[nt]] = to_e4m3(acc[mt][nt][r] + bias_v[nt]);
        }
    }
}

// =====================================================================
// tr_cast: 64(N)x128(K) transpose+cast tile, 512 threads.
// Read: aligned float2 pairs (row addresses always 8B-aligned: even idx).
// Convert BEFORE LDS via HW cvt_pk (fp8 byte tile [128][68], 4x smaller
// than f32, pad 4B to spread banks). Output: 64 rows x 128B via uint4.
// K < 128 rows are zero-filled (t1_W pads bytes 64..127 of each row).
// =====================================================================
__device__ __forceinline__ void tr_cast(const float* __restrict__ W, u8* __restrict__ WT,
                                        int K, int N, int Kpad, float scale,
                                        int bx, int by, u8* ldsb /* >= 128*68 */) {
    int n0 = bx * 64, k0 = by * 128;
    int c4 = threadIdx.x & 15;           // col quad 0..15
    int rg = threadIdx.x >> 4;           // 0..31
    int n = n0 + c4 * 4;
    #pragma unroll
    for (int j = 0; j < 4; j++) {
        int kr = rg + j * 32;            // 0..127
        int k = k0 + kr;
        float2 v01 = make_float2(0.f, 0.f), v23 = make_float2(0.f, 0.f);
        if (k < K) {
            const float* row = W + (size_t)k * N;
            if (n + 3 < N) {
                v01 = *reinterpret_cast<const float2*>(row + n);
                v23 = *reinterpret_cast<const float2*>(row + n + 2);
            } else {
                if (n     < N) v01.x = row[n];
                if (n + 1 < N) v01.y = row[n + 1];
                if (n + 2 < N) v23.x = row[n + 2];
                if (n + 3 < N) v23.y = row[n + 3];
            }
        }
        unsigned pk = cvt4(v01.x * scale, v01.y * scale, v23.x * scale, v23.y * scale);
        *reinterpret_cast<unsigned*>(ldsb + kr * 68 + c4 * 4) = pk;
    }
    __syncthreads();
    int nn = threadIdx.x >> 3, kb = (threadIdx.x & 7) * 16;   // nn 0..63, kb 0..112
    union { u8 b[16]; uint4 u; } o;
    #pragma unroll
    for (int j = 0; j < 16; j++) o.b[j] = ldsb[(kb + j) * 68 + nn];
    *reinterpret_cast<uint4*>(WT + (size_t)(n0 + nn) * Kpad + k0 + kb) = o.u;
}

// =====================================================================
// prep1: inp cast + proj-weight transposes + init. 512 threads/block.
// =====================================================================
#define P1_CAST 256    // 256 x 512 thr x 2 float4 = 262144 float4s
#define P1_T0P   32    // 4 bx x 8 by  (t0_pW: 1024x256)
#define P1_T1P   16    // 2 bx x 8 by  (t1_pW: 1024x64; bx=1 zero-fills pad rows)
#define P1_INIT   8    // 8 x 512 = 4096

__global__ void prep1_kernel(const float* __restrict__ inp, const int* __restrict__ labels,
                             const float* __restrict__ t0_pW, const float* __restrict__ t0_pb,
                             const float* __restrict__ t1_pW, const float* __restrict__ t1_pb,
                             u8* __restrict__ inp_f8, u8* __restrict__ fpW8,
                             float* __restrict__ acc6, int* __restrict__ tgts,
                             float* __restrict__ pbias, int* __restrict__ cnt,
                             float* __restrict__ out) {
    __shared__ __align__(16) u8 ldsb[128 * 68];
    int b = blockIdx.x;
    if (b < P1_CAST) {
        #pragma unroll
        for (int h = 0; h < 2; h++) {
            int i = b * 1024 + h * 512 + threadIdx.x;    // < 262144
            float4 v = reinterpret_cast<const float4*>(inp)[i];
            reinterpret_cast<unsigned*>(inp_f8)[i] = cvt4(v.x, v.y, v.z, v.w);
        }
    } else if (b < P1_CAST + P1_T0P) {
        int r = b - P1_CAST;
        tr_cast(t0_pW, fpW8, HID, P0, HID, 32.0f, r & 3, r >> 2, ldsb);
    } else if (b < P1_CAST + P1_T0P + P1_T1P) {
        int r = b - (P1_CAST + P1_T0P);
        tr_cast(t1_pW, fpW8 + 256 * HID, HID, P1, HID, 32.0f, r & 1, r >> 1, ldsb);
    } else {
        int r = b - (P1_CAST + P1_T0P + P1_T1P);
        int t = r * 512 + threadIdx.x;          // t < 4096
        for (int j = t; j < 6 * M_TOK; j += M_TOK) acc6[j] = 0.0f;
        if (t == 0) { out[0] = 0.0f; cnt[0] = 0; }
        if (t < PFUSE) pbias[t] = (t < 256) ? t0_pb[t] : ((t < PREAL) ? t1_pb[t - 256] : 0.0f);
        int lbl = labels[t];
        tgts[t]             = (lbl < 16000) ? lbl : ((lbl < 28000) ? 16000 : 16001);
        int t0 = lbl - 16000; t0 = t0 < 0 ? 0 : (t0 > 11999 ? 11999 : t0);
        int t1 = lbl - 28000; t1 = t1 < 0 ? 0 : (t1 > 7999  ? 7999  : t1);
        tgts[M_TOK + t]     = t0;
        tgts[2 * M_TOK + t] = t1;
    }
}

// =====================================================================
// prep2: big weight transposes FUSED with the proj GEMM blocks.
// head: 252 bx x 8 by = 2016; t0_W: 188 x 2 = 376; t1_W (K=64, rows
// 64..127 auto-zero): 128 x 1; proj: 96.
// =====================================================================
#define P2_HEAD 2016
#define P2_T0W   376
#define P2_T1W   128
#define P2_PROJ   96

__launch_bounds__(512, 4)
__global__ void prep2_kernel(const float* __restrict__ head_W,
                             const float* __restrict__ t0_W, const float* __restrict__ t1_W,
                             const u8* __restrict__ inp_f8, const u8* __restrict__ fpW8,
                             const float* __restrict__ pbias,
                             u8* __restrict__ headW8, u8* __restrict__ t0W8,
                             u8* __restrict__ t1W8, u8* __restrict__ proj8) {
    __shared__ __align__(16) u8 smem[32768];
    int b = blockIdx.x;
    if (b < P2_HEAD) {
        tr_cast(head_W, headW8, HID, NHEAD, HID, 32.0f, b % 252, b / 252, smem);
    } else if (b < P2_HEAD + P2_T0W) {
        int r = b - P2_HEAD;
        tr_cast(t0_W, t0W8, P0, N0, P0, 32.0f, r % 188, r / 188, smem);
    } else if (b < P2_HEAD + P2_T0W + P2_T1W) {
        int r = b - (P2_HEAD + P2_T0W);
        tr_cast(t1_W, t1W8, P1, N1, 128, 32.0f, r, 0, smem);
    } else {
        int r = b - (P2_HEAD + P2_T0W + P2_T1W);
        int m0 = (r & 31) * 128;
        int n0 = (r >> 5) * 128;
        proj_body(inp_f8, fpW8, pbias, proj8, m0, n0, smem, smem + 16384);
    }
}

// ---------------- host launcher ----------------
extern "C" void kernel_launch(void* const* d_in, const int* in_sizes, int n_in,
                              void* d_out, int out_size, void* d_ws, size_t ws_size,
                              hipStream_t stream) {
    const float* inp    = (const float*)d_in[0];
    const int*   labels = (const int*)  d_in[1];
    const float* head_W = (const float*)d_in[2];
    const float* head_b = (const float*)d_in[3];
    const float* t0_pW  = (const float*)d_in[4];
    const float* t0_pb  = (const float*)d_in[5];
    const float* t0_W   = (const float*)d_in[6];
    const float* t0_b   = (const float*)d_in[7];
    const float* t1_pW  = (const float*)d_in[8];
    const float* t1_pb  = (const float*)d_in[9];
    const float* t1_W   = (const float*)d_in[10];
    const float* t1_b   = (const float*)d_in[11];
    float* out = (float*)d_out;

    char* ws = (char*)d_ws;
    size_t off = 0;
    auto alloc = [&](size_t bytes) { char* p = ws + off; off += (bytes + 255) & ~(size_t)255; return p; };
    u8*    inp_f8  = (u8*)   alloc((size_t)M_TOK * HID);
    u8*    headW8  = (u8*)   alloc((size_t)NHEAD_PAD * HID);
    u8*    fpW8    = (u8*)   alloc((size_t)PFUSE * HID);
    u8*    t0W8    = (u8*)   alloc((size_t)N0_PAD * P0);
    u8*    t1W8    = (u8*)   alloc((size_t)N1_PAD * 128);
    u8*    proj8   = (u8*)   alloc((size_t)M_TOK * PFUSE);
    float* acc6    = (float*)alloc(6 * M_TOK * 4);
    int*   tgts    = (int*)  alloc(3 * M_TOK * 4);
    float* pbias   = (float*)alloc(PFUSE * 4);
    int*   cnt     = (int*)  alloc(256);

    // stage 1: everything the proj GEMM needs (inp cast, proj weights, init)
    prep1_kernel<<<P1_CAST + P1_T0P + P1_T1P + P1_INIT, 512, 0, stream>>>(
        inp, labels, t0_pW, t0_pb, t1_pW, t1_pb,
        inp_f8, fpW8, acc6, tgts, pbias, cnt, out);

    // stage 2: big transposes FUSED with proj GEMM (independent blocks)
    prep2_kernel<<<P2_HEAD + P2_T0W + P2_T1W + P2_PROJ, 512, 0, stream>>>(
        head_W, t0_W, t1_W, inp_f8, fpW8, pbias,
        headW8, t0W8, t1W8, proj8);

    // stage 3: all three LSE GEMMs + fused last-block finalize
    Seg s0{inp_f8,      HID,   headW8, HID, head_b, HID, NHEAD, tgts,             acc6,             acc6 + M_TOK,     16 * (NHEAD_PAD / 128)};
    Seg s1{proj8,       PFUSE, t0W8,   P0,  t0_b,   P0,  N0,    tgts + M_TOK,     acc6 + 2 * M_TOK, acc6 + 3 * M_TOK, 16 * (N0_PAD / 128)};
    Seg s2{proj8 + 256, PFUSE, t1W8,   128, t1_b,   128, N1,    tgts + 2 * M_TOK, acc6 + 4 * M_TOK, acc6 + 5 * M_TOK, 16 * (N1_PAD / 128)};
    int nblkTotal = s0.nblk + s1.nblk + s2.nblk;
    gemm_lse3<<<nblkTotal, 512, 0, stream>>>(s0, s1, s2, labels, acc6, cnt, out, nblkTotal);
}

// Round 11
// 289.770 us; speedup vs baseline: 3.0988x; 3.0988x over previous
//
#include <hip/hip_runtime.h>
#include <hip/hip_bf16.h>
#include <cstdint>
#include <cstddef>

// ---------------- problem constants ----------------
#define M_TOK 4096          // B*S = 4*1024 tokens
#define HID   1024
#define NHEAD 16002
#define NHEAD_PAD 16128     // 126*128
#define P0    256
#define N0    12000
#define N0_PAD 12032        // 94*128
#define P1    64
#define N1    8000
#define N1_PAD 8192         // 64*128
#define PFUSE 384           // fused proj width: 256 + 128(pad of 64)
#define PREAL 320           // real cols in fused proj: 256 + 64

typedef unsigned char u8;
typedef float f32x4 __attribute__((ext_vector_type(4)));
typedef int   i32x4 __attribute__((ext_vector_type(4)));
typedef int   i32x8 __attribute__((ext_vector_type(8)));

// async global->LDS, 16B per lane; lds ptr = wave-uniform base, HW scatters lane*16.
__device__ __forceinline__ void load16(const void* g, void* l) {
    __builtin_amdgcn_global_load_lds(
        (__attribute__((address_space(1))) void*)g,
        (__attribute__((address_space(3))) void*)l,
        16, 0, 0);
}

// HW fp8 conversion (gfx950 OCP e4m3, RNE+sat) — v_cvt_pk_fp8_f32, never the
// ~30-op software fallback of the __hip_fp8_e4m3 constructor. [R10-verified]
__device__ __forceinline__ u8 to_e4m3(float f) {
    return (u8)(__builtin_amdgcn_cvt_pk_fp8_f32(f, f, 0, false) & 0xff);
}
__device__ __forceinline__ unsigned cvt4(float x, float y, float z, float w) {
    int r = __builtin_amdgcn_cvt_pk_fp8_f32(x, y, 0, false);
    r = __builtin_amdgcn_cvt_pk_fp8_f32(z, w, r, true);
    return (unsigned)r;
}

union Frag { struct { i32x4 lo, hi; } half; i32x8 v; };

// =====================================================================
// Round-11 lse3: VERBATIM round-9 GEMM (155us fingerprint: VGPR 64,
// LDS 49152, MfmaUtil ~22.5). BM=256 x BN=128, BK=128, 8 waves of the
// proven 64x64 wave tile, single-buffered 48 KB LDS, 2-barrier loop,
// 2 blocks/CU.
//
// L7 (round-10 lesson): NO agent-scope fences / acquire atomics in here.
// The fused-finalize counter pattern compiled to per-block buffer_wbl2 +
// buffer_inv (L2 INVALIDATE), nuking the weight panels other resident
// blocks were streaming -> refetch from L3 at ~450cyc -> 5x wall with
// UNCHANGED FETCH_SIZE (L3 absorbs, HBM counters blind). Separate
// finalize dispatch costs ~5us; L2 poison cost ~620us.
// =====================================================================
struct Seg {
    const u8* A; int lda;
    const u8* BT; int ldb;
    const float* bias; int K; int realN;
    const int* tgt; float* sumexp; float* lab;
    int nblk;   // 16 m-tiles x NT n-tiles(128), NT even; nblk % 32 == 0
};

__launch_bounds__(512, 4)
__global__ void gemm_lse3(Seg s0, Seg s1, Seg s2) {
    __shared__ __align__(16) u8 As[32768];   // 256 x 128
    __shared__ __align__(16) u8 Bs[16384];   // 128 x 128

    int b = blockIdx.x;
    Seg sg; int rel;
    if (b < s0.nblk)                { sg = s0; rel = b; }
    else if (b < s0.nblk + s1.nblk) { sg = s1; rel = b - s0.nblk; }
    else                            { sg = s2; rel = b - s0.nblk - s1.nblk; }
    // L2-locality swizzle: 32-block groups = 16 m-tiles x 2 n-tiles.
    int pair = rel >> 5, inner = rel & 31;
    int m0 = (inner >> 1) * 256;
    int n0 = (pair * 2 + (inner & 1)) * 128;

    const int lda = sg.lda, ldb = sg.ldb;
    const int tid  = threadIdx.x;
    const int lane = tid & 63;
    const int wave = tid >> 6;          // 0..7
    const int wm = wave >> 1, wn = wave & 1;
    const int q = lane >> 4, lrow = lane & 15;
    const int sw = lrow & 7;

    // A staging: 2048 granules (256 rows x 8), 4 loads/thread.
    // B staging: 1024 granules (128 rows x 8), 2 loads/thread.
    int aofs[4], abase[4], bofs[2], bbase[2];
    #pragma unroll
    for (int p = 0; p < 4; p++) {
        int pg = wave * 256 + p * 64 + lane;          // 0..2047
        int row = pg >> 3, gcol = (pg & 7) ^ (row & 7);
        aofs[p]  = row * lda + gcol * 16;
        abase[p] = (wave * 256 + p * 64) * 16;
    }
    #pragma unroll
    for (int p = 0; p < 2; p++) {
        int pg = wave * 128 + p * 64 + lane;          // 0..1023
        int row = pg >> 3, gcol = (pg & 7) ^ (row & 7);
        bofs[p]  = row * ldb + gcol * 16;
        bbase[p] = (wave * 128 + p * 64) * 16;
    }

    f32x4 acc[4][4];
    #pragma unroll
    for (int mt = 0; mt < 4; mt++)
        #pragma unroll
        for (int nt = 0; nt < 4; nt++)
            acc[mt][nt] = (f32x4)(0.0f);

    const u8* Ab = sg.A  + (size_t)m0 * lda;
    const u8* Bb = sg.BT + (size_t)n0 * ldb;

    // fragment LDS byte offsets; +t*2048 per 16-row subtile.
    const int aLo = ((wm * 64 + lrow) * 8 + ((2 * q)     ^ sw)) * 16;
    const int aHi = ((wm * 64 + lrow) * 8 + ((2 * q + 1) ^ sw)) * 16;
    const int bLo = ((wn * 64 + lrow) * 8 + ((2 * q)     ^ sw)) * 16;
    const int bHi = ((wn * 64 + lrow) * 8 + ((2 * q + 1) ^ sw)) * 16;

    for (int k0 = 0; k0 < sg.K; k0 += 128) {
        #pragma unroll
        for (int p = 0; p < 4; p++)
            load16(Ab + k0 + aofs[p], As + abase[p]);
        #pragma unroll
        for (int p = 0; p < 2; p++)
            load16(Bb + k0 + bofs[p], Bs + bbase[p]);
        __syncthreads();   // includes vmcnt(0) drain; 2nd block/CU covers it

        Frag fb[4];
        #pragma unroll
        for (int t = 0; t < 4; t++) {
            fb[t].half.lo = *reinterpret_cast<const i32x4*>(Bs + bLo + t * 2048);
            fb[t].half.hi = *reinterpret_cast<const i32x4*>(Bs + bHi + t * 2048);
        }
        Frag fa[2];
        fa[0].half.lo = *reinterpret_cast<const i32x4*>(As + aLo);
        fa[0].half.hi = *reinterpret_cast<const i32x4*>(As + aHi);
        #pragma unroll
        for (int mt = 0; mt < 4; mt++) {
            if (mt < 3) {
                fa[(mt + 1) & 1].half.lo = *reinterpret_cast<const i32x4*>(As + aLo + (mt + 1) * 2048);
                fa[(mt + 1) & 1].half.hi = *reinterpret_cast<const i32x4*>(As + aHi + (mt + 1) * 2048);
            }
            #pragma unroll
            for (int nt = 0; nt < 4; nt++)
                acc[mt][nt] = __builtin_amdgcn_mfma_scale_f32_16x16x128_f8f6f4(
                    fa[mt & 1].v, fb[nt].v, acc[mt][nt],
                    0, 0,                      // cbsz/blgp = fp8 e4m3
                    0, 0x7F7F7F7F,             // A scale: 2^0
                    0, 0x7A7A7A7A);            // B scale: 2^-5
        }
        __syncthreads();   // reads retired before next overwrite
    }

    // ---- epilogue: C/D (16x16): col = lane&15, row = (lane>>4)*4 + reg
    int colg[4]; float bias_v[4];
    #pragma unroll
    for (int nt = 0; nt < 4; nt++) {
        colg[nt] = n0 + wn * 64 + nt * 16 + lrow;
        bias_v[nt] = (colg[nt] < sg.realN) ? sg.bias[colg[nt]] : 0.0f;
    }

    float* sred = reinterpret_cast<float*>(As);   // [2][256], reuse A LDS

    #pragma unroll
    for (int mt = 0; mt < 4; mt++) {
        int rloc = wm * 64 + mt * 16 + q * 4;     // token row within tile (0..255)
        #pragma unroll
        for (int r = 0; r < 4; r++) {
            int tok = m0 + rloc + r;
            int tg = sg.tgt[tok];
            float ps = 0.0f;
            #pragma unroll
            for (int nt = 0; nt < 4; nt++) {
                if (colg[nt] < sg.realN) {
                    float logit = acc[mt][nt][r] + bias_v[nt];
                    ps += __expf(logit);
                    if (colg[nt] == tg) atomicAdd(&sg.lab[tok], logit);
                }
            }
            ps += __shfl_xor(ps, 1);
            ps += __shfl_xor(ps, 2);
            ps += __shfl_xor(ps, 4);
            ps += __shfl_xor(ps, 8);
            // slice write: (wn, row) written by exactly one lane
            if (lrow == 0) sred[wn * 256 + rloc + r] = ps;
        }
    }
    __syncthreads();
    if (tid < 256) {
        float v = sred[tid] + sred[256 + tid];
        atomicAdd(&sg.sumexp[m0 + tid], v);
    }
}

// =====================================================================
// proj GEMM body (proven 128x128, 8 waves of 64x32), runs as blocks of
// the fused prep2 dispatch. Epilogue uses HW fp8 convert (R10).
// =====================================================================
__device__ __forceinline__ void proj_body(const u8* __restrict__ A, const u8* __restrict__ BT,
                                          const float* __restrict__ bias, u8* __restrict__ out,
                                          int m0, int n0, u8* As, u8* Bs) {
    const int lda = HID, ldb = HID, ldo = PFUSE;
    const int tid  = threadIdx.x;
    const int lane = tid & 63;
    const int wave = tid >> 6;          // 0..7
    const int wm = wave >> 2, wn = wave & 3;
    const int q = lane >> 4, lrow = lane & 15;
    const int sw = lrow & 7;

    int aofs[2], bofs[2], lbase[2];
    #pragma unroll
    for (int p = 0; p < 2; p++) {
        int pg = wave * 128 + p * 64 + lane;
        int row = pg >> 3, gcol = (pg & 7) ^ (row & 7);
        aofs[p]  = row * lda + gcol * 16;
        bofs[p]  = row * ldb + gcol * 16;
        lbase[p] = (wave * 128 + p * 64) * 16;
    }

    f32x4 acc[4][2];
    #pragma unroll
    for (int mt = 0; mt < 4; mt++)
        #pragma unroll
        for (int nt = 0; nt < 2; nt++)
            acc[mt][nt] = (f32x4)(0.0f);

    const u8* Ab = A  + (size_t)m0 * lda;
    const u8* Bb = BT + (size_t)n0 * ldb;

    const int aLo = ((wm * 64 + lrow) * 8 + ((2 * q)     ^ sw)) * 16;
    const int aHi = ((wm * 64 + lrow) * 8 + ((2 * q + 1) ^ sw)) * 16;
    const int bLo = ((wn * 32 + lrow) * 8 + ((2 * q)     ^ sw)) * 16;
    const int bHi = ((wn * 32 + lrow) * 8 + ((2 * q + 1) ^ sw)) * 16;

    for (int k0 = 0; k0 < HID; k0 += 128) {
        #pragma unroll
        for (int p = 0; p < 2; p++) {
            load16(Ab + k0 + aofs[p], As + lbase[p]);
            load16(Bb + k0 + bofs[p], Bs + lbase[p]);
        }
        __syncthreads();
        Frag fb[2];
        #pragma unroll
        for (int t = 0; t < 2; t++) {
            fb[t].half.lo = *reinterpret_cast<const i32x4*>(Bs + bLo + t * 2048);
            fb[t].half.hi = *reinterpret_cast<const i32x4*>(Bs + bHi + t * 2048);
        }
        #pragma unroll
        for (int mt = 0; mt < 4; mt++) {
            Frag fa;
            fa.half.lo = *reinterpret_cast<const i32x4*>(As + aLo + mt * 2048);
            fa.half.hi = *reinterpret_cast<const i32x4*>(As + aHi + mt * 2048);
            #pragma unroll
            for (int nt = 0; nt < 2; nt++)
                acc[mt][nt] = __builtin_amdgcn_mfma_scale_f32_16x16x128_f8f6f4(
                    fa.v, fb[nt].v, acc[mt][nt],
                    0, 0, 0, 0x7F7F7F7F, 0, 0x7A7A7A7A);
        }
        __syncthreads();
    }

    int colg[2]; float bias_v[2];
    #pragma unroll
    for (int nt = 0; nt < 2; nt++) {
        colg[nt] = n0 + wn * 32 + nt * 16 + lrow;
        bias_v[nt] = (colg[nt] < PREAL) ? bias[colg[nt]] : 0.0f;
    }
    #pragma unroll
    for (int mt = 0; mt < 4; mt++) {
        int rowb = m0 + wm * 64 + mt * 16 + q * 4;
        #pragma unroll
        for (int r = 0; r < 4; r++) {
            int tok = rowb + r;
            #pragma unroll
            for (int nt = 0; nt < 2; nt++)
                out[(size_t)tok * ldo + colg[nt]] = to_e4m3(acc[mt][nt][r] + bias_v[nt]);
        }
    }
}

// =====================================================================
// tr_cast (R10-verified): 64(N)x128(K) transpose+cast tile, 512 threads.
// Convert BEFORE LDS via HW cvt_pk (fp8 byte tile [128][68]); aligned
// float2 reads; uint4 output stores. K<128 rows zero-filled.
// =====================================================================
__device__ __forceinline__ void tr_cast(const float* __restrict__ W, u8* __restrict__ WT,
                                        int K, int N, int Kpad, float scale,
                                        int bx, int by, u8* ldsb /* >= 128*68 */) {
    int n0 = bx * 64, k0 = by * 128;
    int c4 = threadIdx.x & 15;           // col quad 0..15
    int rg = threadIdx.x >> 4;           // 0..31
    int n = n0 + c4 * 4;
    #pragma unroll
    for (int j = 0; j < 4; j++) {
        int kr = rg + j * 32;            // 0..127
        int k = k0 + kr;
        float2 v01 = make_float2(0.f, 0.f), v23 = make_float2(0.f, 0.f);
        if (k < K) {
            const float* row = W + (size_t)k * N;
            if (n + 3 < N) {
                v01 = *reinterpret_cast<const float2*>(row + n);
                v23 = *reinterpret_cast<const float2*>(row + n + 2);
            } else {
                if (n     < N) v01.x = row[n];
                if (n + 1 < N) v01.y = row[n + 1];
                if (n + 2 < N) v23.x = row[n + 2];
                if (n + 3 < N) v23.y = row[n + 3];
            }
        }
        unsigned pk = cvt4(v01.x * scale, v01.y * scale, v23.x * scale, v23.y * scale);
        *reinterpret_cast<unsigned*>(ldsb + kr * 68 + c4 * 4) = pk;
    }
    __syncthreads();
    int nn = threadIdx.x >> 3, kb = (threadIdx.x & 7) * 16;   // nn 0..63, kb 0..112
    union { u8 b[16]; uint4 u; } o;
    #pragma unroll
    for (int j = 0; j < 16; j++) o.b[j] = ldsb[(kb + j) * 68 + nn];
    *reinterpret_cast<uint4*>(WT + (size_t)(n0 + nn) * Kpad + k0 + kb) = o.u;
}

// =====================================================================
// prep1: inp cast + proj-weight transposes + init. 512 threads/block.
// =====================================================================
#define P1_CAST 256    // 256 x 512 thr x 2 float4 = 262144 float4s
#define P1_T0P   32    // 4 bx x 8 by  (t0_pW: 1024x256)
#define P1_T1P   16    // 2 bx x 8 by  (t1_pW: 1024x64; bx=1 zero-fills pad rows)
#define P1_INIT   8    // 8 x 512 = 4096

__global__ void prep1_kernel(const float* __restrict__ inp, const int* __restrict__ labels,
                             const float* __restrict__ t0_pW, const float* __restrict__ t0_pb,
                             const float* __restrict__ t1_pW, const float* __restrict__ t1_pb,
                             u8* __restrict__ inp_f8, u8* __restrict__ fpW8,
                             float* __restrict__ acc6, int* __restrict__ tgts,
                             float* __restrict__ pbias, float* __restrict__ out) {
    __shared__ __align__(16) u8 ldsb[128 * 68];
    int b = blockIdx.x;
    if (b < P1_CAST) {
        #pragma unroll
        for (int h = 0; h < 2; h++) {
            int i = b * 1024 + h * 512 + threadIdx.x;    // < 262144
            float4 v = reinterpret_cast<const float4*>(inp)[i];
            reinterpret_cast<unsigned*>(inp_f8)[i] = cvt4(v.x, v.y, v.z, v.w);
        }
    } else if (b < P1_CAST + P1_T0P) {
        int r = b - P1_CAST;
        tr_cast(t0_pW, fpW8, HID, P0, HID, 32.0f, r & 3, r >> 2, ldsb);
    } else if (b < P1_CAST + P1_T0P + P1_T1P) {
        int r = b - (P1_CAST + P1_T0P);
        tr_cast(t1_pW, fpW8 + 256 * HID, HID, P1, HID, 32.0f, r & 1, r >> 1, ldsb);
    } else {
        int r = b - (P1_CAST + P1_T0P + P1_T1P);
        int t = r * 512 + threadIdx.x;          // t < 4096
        for (int j = t; j < 6 * M_TOK; j += M_TOK) acc6[j] = 0.0f;
        if (t == 0) out[0] = 0.0f;
        if (t < PFUSE) pbias[t] = (t < 256) ? t0_pb[t] : ((t < PREAL) ? t1_pb[t - 256] : 0.0f);
        int lbl = labels[t];
        tgts[t]             = (lbl < 16000) ? lbl : ((lbl < 28000) ? 16000 : 16001);
        int t0 = lbl - 16000; t0 = t0 < 0 ? 0 : (t0 > 11999 ? 11999 : t0);
        int t1 = lbl - 28000; t1 = t1 < 0 ? 0 : (t1 > 7999  ? 7999  : t1);
        tgts[M_TOK + t]     = t0;
        tgts[2 * M_TOK + t] = t1;
    }
}

// =====================================================================
// prep2: big weight transposes FUSED with the proj GEMM blocks.
// head: 252 bx x 8 by = 2016; t0_W: 188 x 2 = 376; t1_W (K=64): 128 x 1;
// proj: 96.
// =====================================================================
#define P2_HEAD 2016
#define P2_T0W   376
#define P2_T1W   128
#define P2_PROJ   96

__launch_bounds__(512, 4)
__global__ void prep2_kernel(const float* __restrict__ head_W,
                             const float* __restrict__ t0_W, const float* __restrict__ t1_W,
                             const u8* __restrict__ inp_f8, const u8* __restrict__ fpW8,
                             const float* __restrict__ pbias,
                             u8* __restrict__ headW8, u8* __restrict__ t0W8,
                             u8* __restrict__ t1W8, u8* __restrict__ proj8) {
    __shared__ __align__(16) u8 smem[32768];
    int b = blockIdx.x;
    if (b < P2_HEAD) {
        tr_cast(head_W, headW8, HID, NHEAD, HID, 32.0f, b % 252, b / 252, smem);
    } else if (b < P2_HEAD + P2_T0W) {
        int r = b - P2_HEAD;
        tr_cast(t0_W, t0W8, P0, N0, P0, 32.0f, r % 188, r / 188, smem);
    } else if (b < P2_HEAD + P2_T0W + P2_T1W) {
        int r = b - (P2_HEAD + P2_T0W);
        tr_cast(t1_W, t1W8, P1, N1, 128, 32.0f, r, 0, smem);
    } else {
        int r = b - (P2_HEAD + P2_T0W + P2_T1W);
        int m0 = (r & 31) * 128;
        int n0 = (r >> 5) * 128;
        proj_body(inp_f8, fpW8, pbias, proj8, m0, n0, smem, smem + 16384);
    }
}

// ---------------- finalize: per-token loss, mask, mean (separate dispatch;
// L7: keeping this out of gemm_lse3 avoids per-block L2 invalidation) ----
__global__ void finalize_kernel(const int* __restrict__ labels, const float* __restrict__ acc6,
                                float* __restrict__ out) {
    int t = blockIdx.x * blockDim.x + threadIdx.x;   // 4096 threads
    const float* sumH = acc6;
    const float* labH = acc6 + M_TOK;
    const float* sum0 = acc6 + 2 * M_TOK;
    const float* lab0 = acc6 + 3 * M_TOK;
    const float* sum1 = acc6 + 4 * M_TOK;
    const float* lab1 = acc6 + 5 * M_TOK;
    int lbl = labels[t];
    float l = 0.0f;
    if (lbl != 0) {
        l = logf(sumH[t]) - labH[t];
        if (lbl >= 16000 && lbl < 28000) l += logf(sum0[t]) - lab0[t];
        else if (lbl >= 28000)           l += logf(sum1[t]) - lab1[t];
    }
    l *= (1.0f / (float)M_TOK);
    #pragma unroll
    for (int off = 1; off < 64; off <<= 1) l += __shfl_xor(l, off);
    __shared__ float red[4];
    if ((threadIdx.x & 63) == 0) red[threadIdx.x >> 6] = l;
    __syncthreads();
    if (threadIdx.x == 0) atomicAdd(out, red[0] + red[1] + red[2] + red[3]);
}

// ---------------- host launcher ----------------
extern "C" void kernel_launch(void* const* d_in, const int* in_sizes, int n_in,
                              void* d_out, int out_size, void* d_ws, size_t ws_size,
                              hipStream_t stream) {
    const float* inp    = (const float*)d_in[0];
    const int*   labels = (const int*)  d_in[1];
    const float* head_W = (const float*)d_in[2];
    const float* head_b = (const float*)d_in[3];
    const float* t0_pW  = (const float*)d_in[4];
    const float* t0_pb  = (const float*)d_in[5];
    const float* t0_W   = (const float*)d_in[6];
    const float* t0_b   = (const float*)d_in[7];
    const float* t1_pW  = (const float*)d_in[8];
    const float* t1_pb  = (const float*)d_in[9];
    const float* t1_W   = (const float*)d_in[10];
    const float* t1_b   = (const float*)d_in[11];
    float* out = (float*)d_out;

    char* ws = (char*)d_ws;
    size_t off = 0;
    auto alloc = [&](size_t bytes) { char* p = ws + off; off += (bytes + 255) & ~(size_t)255; return p; };
    u8*    inp_f8  = (u8*)   alloc((size_t)M_TOK * HID);
    u8*    headW8  = (u8*)   alloc((size_t)NHEAD_PAD * HID);
    u8*    fpW8    = (u8*)   alloc((size_t)PFUSE * HID);
    u8*    t0W8    = (u8*)   alloc((size_t)N0_PAD * P0);
    u8*    t1W8    = (u8*)   alloc((size_t)N1_PAD * 128);
    u8*    proj8   = (u8*)   alloc((size_t)M_TOK * PFUSE);
    float* acc6    = (float*)alloc(6 * M_TOK * 4);
    int*   tgts    = (int*)  alloc(3 * M_TOK * 4);
    float* pbias   = (float*)alloc(PFUSE * 4);

    // stage 1: everything the proj GEMM needs (inp cast, proj weights, init)
    prep1_kernel<<<P1_CAST + P1_T0P + P1_T1P + P1_INIT, 512, 0, stream>>>(
        inp, labels, t0_pW, t0_pb, t1_pW, t1_pb,
        inp_f8, fpW8, acc6, tgts, pbias, out);

    // stage 2: big transposes FUSED with proj GEMM (independent blocks)
    prep2_kernel<<<P2_HEAD + P2_T0W + P2_T1W + P2_PROJ, 512, 0, stream>>>(
        head_W, t0_W, t1_W, inp_f8, fpW8, pbias,
        headW8, t0W8, t1W8, proj8);

    // stage 3: all three LSE GEMMs in one dispatch (head first = longest)
    Seg s0{inp_f8,      HID,   headW8, HID, head_b, HID, NHEAD, tgts,             acc6,             acc6 + M_TOK,     16 * (NHEAD_PAD / 128)};
    Seg s1{proj8,       PFUSE, t0W8,   P0,  t0_b,   P0,  N0,    tgts + M_TOK,     acc6 + 2 * M_TOK, acc6 + 3 * M_TOK, 16 * (N0_PAD / 128)};
    Seg s2{proj8 + 256, PFUSE, t1W8,   128, t1_b,   128, N1,    tgts + 2 * M_TOK, acc6 + 4 * M_TOK, acc6 + 5 * M_TOK, 16 * (N1_PAD / 128)};
    gemm_lse3<<<s0.nblk + s1.nblk + s2.nblk, 512, 0, stream>>>(s0, s1, s2);

    // stage 4: reduce to scalar mean
    finalize_kernel<<<M_TOK / 256, 256, 0, stream>>>(labels, acc6, out);
}